// Round 18
// baseline (471.044 us; speedup 1.0000x reference)
//
#include <hip/hip_runtime.h>
#include <cmath>

#define BSZ 8
#define TT  1024
#define EE  512
#define HH  8
#define CUc 6
#define HDD 64

typedef __bf16 bf16;
typedef __attribute__((ext_vector_type(4))) float f32x4;
typedef __attribute__((ext_vector_type(8))) float f32x8;
typedef __attribute__((ext_vector_type(4))) bf16  bf16x4;
typedef __attribute__((ext_vector_type(8))) bf16  bf16x8;

static __device__ __forceinline__ f32x4 mfma16(bf16x8 a, bf16x8 b, f32x4 c) {
    return __builtin_amdgcn_mfma_f32_16x16x32_bf16(a, b, c, 0, 0, 0);
}
static __device__ __forceinline__ void glds16(const bf16* g, bf16* l) {
    __builtin_amdgcn_global_load_lds((const __attribute__((address_space(1))) void*)g,
                                     (__attribute__((address_space(3))) void*)l, 16, 0, 0);
}

// ---------------------------------------------------------------- k_split_all: 4 weight mats
__global__ __launch_bounds__(256) void k_split_all(
    const float* __restrict__ wq, const float* __restrict__ wk,
    const float* __restrict__ wv, const float* __restrict__ wo,
    bf16* __restrict__ wqh, bf16* __restrict__ wql,
    bf16* __restrict__ wkh, bf16* __restrict__ wkl,
    bf16* __restrict__ wvh, bf16* __restrict__ woh)
{
    const float* src; bf16* hi; bf16* lo;
    switch (blockIdx.y) {
        case 0: src = wq; hi = wqh; lo = wql;     break;
        case 1: src = wk; hi = wkh; lo = wkl;     break;
        case 2: src = wv; hi = wvh; lo = nullptr; break;
        default: src = wo; hi = woh; lo = nullptr; break;
    }
    const int i = (blockIdx.x * 256 + threadIdx.x) * 8;
    f32x8 v = *(const f32x8*)(src + i);
    bf16x8 h8, l8;
#pragma unroll
    for (int k = 0; k < 8; ++k) {
        bf16 h = (bf16)v[k];
        h8[k] = h;
        l8[k] = (bf16)(v[k] - (float)h);
    }
    *(bf16x8*)(hi + i) = h8;
    if (lo) *(bf16x8*)(lo + i) = l8;
}

// ---------------------------------------------------------------- k_pre: ubias2 (2048 blocks) + proj2 (1024 blocks)
// merged launch, roles interleaved 2:1 so both run concurrently from dispatch 0.
__global__ __launch_bounds__(256) void k_pre(
    // ubias args
    const float* __restrict__ u, const unsigned char* __restrict__ umask,
    const float* __restrict__ wu, const float* __restrict__ bu,
    float* __restrict__ A,
    // proj args
    const float* __restrict__ x,
    const bf16* __restrict__ wqh, const bf16* __restrict__ wql,
    const bf16* __restrict__ wkh, const bf16* __restrict__ wkl,
    const bf16* __restrict__ wvh,
    bf16* __restrict__ Qh, bf16* __restrict__ Ql,
    bf16* __restrict__ Kh, bf16* __restrict__ Kl,
    bf16* __restrict__ Vt)
{
    __shared__ __align__(16) unsigned char msk[64][64];   // ubias role only
    const int g   = blockIdx.x;
    const int grp = g / 3, rem = g - grp * 3;

    if (rem < 2) {
        // ================= ubias role: ui in [0,2048) =================
        const int ui = grp * 2 + rem;
        const int b  = ui >> 8;
        const int i0 = ((ui >> 4) & 15) * 64;
        const int j0 = (ui & 15) * 64;
        const int t  = threadIdx.x;

        {
            const int jj  = t >> 2;
            const int seg = (t & 3) * 16;
            *(uint4*)(&msk[jj][seg]) =
                *(const uint4*)(umask + ((size_t)b * TT + (j0 + jj)) * TT + i0 + seg);
        }
        float wuv[HH][CUc], buv[HH];
#pragma unroll
        for (int h = 0; h < HH; ++h) {
            buv[h] = bu[h];
#pragma unroll
            for (int c = 0; c < CUc; ++c) wuv[h][c] = wu[h * CUc + c];
        }
        __syncthreads();

        const int j = j0 + (t & 63);
        for (int ii = (t >> 6); ii < 64; ii += 4) {
            const int i = i0 + ii;
            float uv[CUc];
#pragma unroll
            for (int c = 0; c < CUc; ++c)
                uv[c] = u[(((size_t)b * CUc + c) * TT + i) * TT + j];
            const bool mk = msk[t & 63][ii] != 0;
#pragma unroll
            for (int h = 0; h < HH; ++h) {
                float v = buv[h];
#pragma unroll
                for (int c = 0; c < CUc; ++c) v += uv[c] * wuv[h][c];
                if (mk) v = -INFINITY;
                bf16* ub = (bf16*)(A + ((size_t)(b * HH + h) * TT + (i & ~15)) * TT);
                ub[(i & 15) * TT + j] = (bf16)v;
            }
        }
    } else {
        // ================= proj role: p in [0,1024) =================
        const int p  = grp;
        const int rb = p & 127;
        const int cb = p >> 7;
        const int wid = threadIdx.x >> 6;
        const int l   = threadIdx.x & 63;
        const int lg = l >> 4, lr = l & 15;
        const int row = rb * 64 + wid * 16 + lr;

        f32x4 aq[4], ak[4], av[4];
#pragma unroll
        for (int c = 0; c < 4; ++c) {
            aq[c] = f32x4{0.f,0.f,0.f,0.f}; ak[c] = f32x4{0.f,0.f,0.f,0.f}; av[c] = f32x4{0.f,0.f,0.f,0.f};
        }

        for (int ks = 0; ks < 16; ++ks) {
            const int e0 = ks * 32 + lg * 8;
            f32x8 xv = *(const f32x8*)(x + (size_t)row * EE + e0);
            bf16x8 xh, xl;
#pragma unroll
            for (int i = 0; i < 8; ++i) {
                bf16 h = (bf16)xv[i];
                xh[i] = h;
                xl[i] = (bf16)(xv[i] - (float)h);
            }
#pragma unroll
            for (int c = 0; c < 4; ++c) {
                const int f = cb * 64 + c * 16 + lr;
                const size_t wo = (size_t)f * EE + e0;
                bf16x8 qh = *(const bf16x8*)(wqh + wo);
                bf16x8 ql = *(const bf16x8*)(wql + wo);
                bf16x8 kh = *(const bf16x8*)(wkh + wo);
                bf16x8 kl = *(const bf16x8*)(wkl + wo);
                bf16x8 vh = *(const bf16x8*)(wvh + wo);
                aq[c] = mfma16(xh, qh, aq[c]); aq[c] = mfma16(xh, ql, aq[c]); aq[c] = mfma16(xl, qh, aq[c]);
                ak[c] = mfma16(xh, kh, ak[c]); ak[c] = mfma16(xh, kl, ak[c]); ak[c] = mfma16(xl, kh, ak[c]);
                av[c] = mfma16(xh, vh, av[c]);
            }
        }

#pragma unroll
        for (int c = 0; c < 4; ++c)
#pragma unroll
            for (int r = 0; r < 4; ++r) {
                const int orow = rb * 64 + wid * 16 + lg * 4 + r;
                const int b = orow >> 10, t = orow & 1023;
                const int f = cb * 64 + c * 16 + lr;
                const int h = f >> 6, d = f & 63;
                const size_t idx = ((size_t)(b * HH + h) * TT + t) * HDD + d;
                float vq = aq[c][r];
                bf16 qhi = (bf16)vq; Qh[idx] = qhi; Ql[idx] = (bf16)(vq - (float)qhi);
                float vk = ak[c][r];
                bf16 khi = (bf16)vk; Kh[idx] = khi; Kl[idx] = (bf16)(vk - (float)khi);
                Vt[(((size_t)(b * HH + h) * HDD + d) * TT) + t] = (bf16)av[c][r];
            }
    }
}

// ---------------------------------------------------------------- kf10: LDS-tiled flash attention
__global__ __launch_bounds__(512, 1) void kf10(
    const bf16* __restrict__ Qh, const bf16* __restrict__ Ql,
    const bf16* __restrict__ Kh, const bf16* __restrict__ Kl,
    const bf16* __restrict__ Vt,
    float* __restrict__ A, bf16* __restrict__ ctx)
{
    const int g  = blockIdx.x;
    const int b  = g & 7;                 // XCD g%8 -> batch b (K/V/Q L2-local)
    const int hh = g >> 6;                // head, changes slowest
    const int ib = (g >> 3) & 7;
    const int bh = b * HH + hh;
    const int i0 = ib * 128;
    const int w  = threadIdx.x >> 6;
    const int l  = threadIdx.x & 63;
    const int lg = l >> 4, lr = l & 15;
    const int i16c = ib * 8 + w;          // wave's 16-row chunk id
    const int iw   = i0 + w * 16;

    __shared__ __align__(16) bf16 KHL[2][8192];   // [buf][row*64 + slot*8], slot = seg^(row&7)
    __shared__ __align__(16) bf16 KLL[2][8192];
    __shared__ __align__(16) bf16 VL [2][8192];   // [buf][d*128 + slot*8], slot=(s&8)|((s^(d&7))&7)
    __shared__ __align__(16) bf16 P  [8][2048];   // per-wave 16x128, same XOR scheme
    __shared__ float mh[8][16][12];               // [w][row][tile0..7, 8=S]

    const bf16* KhG = Kh + (size_t)bh * TT * HDD;
    const bf16* KlG = Kl + (size_t)bh * TT * HDD;
    const bf16* VtG = Vt + (size_t)bh * HDD * TT;
    bf16* Aw = (bf16*)(A + ((size_t)bh * TT + i16c * 16) * TT);  // wave's 16-row span (64KB)

    // ---- Q fragments (once)
    const bf16* qph = Qh + ((size_t)bh * TT + iw) * HDD;
    const bf16* qpl = Ql + ((size_t)bh * TT + iw) * HDD;
    bf16x8 qh0 = *(const bf16x8*)(qph + lr * HDD + lg * 8);
    bf16x8 qh1 = *(const bf16x8*)(qph + lr * HDD + 32 + lg * 8);
    bf16x8 ql0 = *(const bf16x8*)(qpl + lr * HDD + lg * 8);
    bf16x8 ql1 = *(const bf16x8*)(qpl + lr * HDD + 32 + lg * 8);

    // ---- staging: wave handles units w*6 .. w*6+5 (48 x 1KB per tile)
    auto stage = [&](int buf, int t) {
        const int j0 = t * 128;
#pragma unroll
        for (int k = 0; k < 6; ++k) {
            const int gu = w * 6 + k;
            if (gu < 16) {                     // Kh: unit u = 8 rows of 128B
                const int u = gu;
                const int jr = u * 8 + (l >> 3), s = l & 7;
                glds16(KhG + (size_t)(j0 + jr) * HDD + ((s ^ (jr & 7)) * 8),
                       &KHL[buf][u * 512]);
            } else if (gu < 32) {
                const int u = gu - 16;
                const int jr = u * 8 + (l >> 3), s = l & 7;
                glds16(KlG + (size_t)(j0 + jr) * HDD + ((s ^ (jr & 7)) * 8),
                       &KLL[buf][u * 512]);
            } else {                           // V: unit u = 4 rows of 256B
                const int u = gu - 32;
                const int d = u * 4 + (l >> 4), s = l & 15;
                const int q = (s & 8) | ((s ^ (d & 7)) & 7);
                glds16(VtG + (size_t)d * TT + j0 + q * 8,
                       &VL[buf][u * 512]);
            }
        }
    };

    float m_run[4], s_run[4];
    f32x4 cacc[4];
#pragma unroll
    for (int r = 0; r < 4; ++r) { m_run[r] = -INFINITY; s_run[r] = 0.f; }
#pragma unroll
    for (int dt = 0; dt < 4; ++dt) cacc[dt] = f32x4{0.f,0.f,0.f,0.f};

    stage(0, 0);
    __syncthreads();

    for (int t = 0; t < 8; ++t) {
        const int buf = t & 1;

        // UB tile loads (global, consumed after QK^T)
        bf16x8 ubr[4];
#pragma unroll
        for (int q = 0; q < 4; ++q) {
            const int r = q * 4 + (l >> 4), s = l & 15;
            ubr[q] = *(const bf16x8*)(Aw + (size_t)r * TT + t * 128 + s * 8);
        }
        if (t < 7) stage(buf ^ 1, t + 1);

        // ---- QK^T from swizzled LDS
        f32x4 s8[8];
#pragma unroll
        for (int jt2 = 0; jt2 < 8; ++jt2) {
            const int jr = jt2 * 16 + lr;
            const int x7 = jr & 7;
            bf16x8 kh0 = *(const bf16x8*)&KHL[buf][jr * 64 + ((lg       ^ x7) * 8)];
            bf16x8 kh1 = *(const bf16x8*)&KHL[buf][jr * 64 + (((lg + 4) ^ x7) * 8)];
            bf16x8 kl0 = *(const bf16x8*)&KLL[buf][jr * 64 + ((lg       ^ x7) * 8)];
            bf16x8 kl1 = *(const bf16x8*)&KLL[buf][jr * 64 + (((lg + 4) ^ x7) * 8)];
            f32x4 acc = f32x4{0.f,0.f,0.f,0.f};
            acc = mfma16(qh0, kh0, acc); acc = mfma16(qh1, kh1, acc);
            acc = mfma16(qh0, kl0, acc); acc = mfma16(qh1, kl1, acc);
            acc = mfma16(ql0, kh0, acc); acc = mfma16(ql1, kh1, acc);
            s8[jt2] = acc;
        }

        // ---- ub add: bounce ubr through P[w] (transposed, XOR layout)
#pragma unroll
        for (int q = 0; q < 4; ++q) {
            const int r = q * 4 + (l >> 4), s = l & 15;
            const int slot = (s & 8) | ((s ^ (r & 7)) & 7);
            *(bf16x8*)&P[w][r * 128 + slot * 8] = ubr[q];
        }
#pragma unroll
        for (int jt2 = 0; jt2 < 8; ++jt2)
#pragma unroll
            for (int r = 0; r < 4; ++r) {
                const int row = lg * 4 + r, col = jt2 * 16 + lr;
                const int sg = col >> 3;
                const int slot = (sg & 8) | ((sg ^ (row & 7)) & 7);
                s8[jt2][r] = s8[jt2][r] * 8.0f + (float)P[w][row * 128 + slot * 8 + (col & 7)];
            }

        // ---- online softmax
        float tm[4];
#pragma unroll
        for (int r = 0; r < 4; ++r) {
            float mm = s8[0][r];
#pragma unroll
            for (int jt2 = 1; jt2 < 8; ++jt2) mm = fmaxf(mm, s8[jt2][r]);
            tm[r] = mm;
        }
#pragma unroll
        for (int off = 1; off < 16; off <<= 1)
#pragma unroll
            for (int r = 0; r < 4; ++r) tm[r] = fmaxf(tm[r], __shfl_xor(tm[r], off));
        float mnew[4], mexp[4], e[4];
#pragma unroll
        for (int r = 0; r < 4; ++r) {
            mnew[r] = fmaxf(m_run[r], tm[r]);
            mexp[r] = (mnew[r] == -INFINITY) ? 0.f : mnew[r];
            e[r]    = (m_run[r] == -INFINITY) ? 0.f : __expf(m_run[r] - mexp[r]);
            m_run[r] = mnew[r];
        }
#pragma unroll
        for (int dt = 0; dt < 4; ++dt)
#pragma unroll
            for (int r = 0; r < 4; ++r) cacc[dt][r] *= e[r];

        float psum[4] = {0.f, 0.f, 0.f, 0.f};
#pragma unroll
        for (int jt2 = 0; jt2 < 8; ++jt2)
#pragma unroll
            for (int r = 0; r < 4; ++r) {
                const float p = __expf(s8[jt2][r] - mexp[r]);
                psum[r] += p;
                const int row = lg * 4 + r, col = jt2 * 16 + lr;
                const int sg = col >> 3;
                const int slot = (sg & 8) | ((sg ^ (row & 7)) & 7);
                P[w][row * 128 + slot * 8 + (col & 7)] = (bf16)p;
            }
#pragma unroll
        for (int off = 1; off < 16; off <<= 1)
#pragma unroll
            for (int r = 0; r < 4; ++r) psum[r] += __shfl_xor(psum[r], off);
#pragma unroll
        for (int r = 0; r < 4; ++r) s_run[r] = s_run[r] * e[r] + psum[r];
        if (lr == 0)
#pragma unroll
            for (int r = 0; r < 4; ++r) mh[w][lg * 4 + r][t] = mnew[r];

        // ---- park p (bf16) in the spare half of the f32 row-span
#pragma unroll
        for (int q = 0; q < 4; ++q) {
            const int r = q * 4 + (l >> 4), s = l & 15;
            const int slot = (s & 8) | ((s ^ (r & 7)) & 7);
            bf16x8 pv = *(const bf16x8*)&P[w][r * 128 + slot * 8];
            *(bf16x8*)(Aw + (size_t)r * 2048 + 1024 + t * 128 + s * 8) = pv;
        }

        // ---- PV from swizzled P and V
#pragma unroll
        for (int ks = 0; ks < 4; ++ks) {
            const int sg = ks * 4 + lg;
            const int ps = (sg & 8) | ((sg ^ (lr & 7)) & 7);
            bf16x8 a = *(const bf16x8*)&P[w][lr * 128 + ps * 8];
#pragma unroll
            for (int dt = 0; dt < 4; ++dt) {
                const int d = dt * 16 + lr;
                const int vs = (sg & 8) | ((sg ^ (d & 7)) & 7);
                bf16x8 bv = *(const bf16x8*)&VL[buf][d * 128 + vs * 8];
                cacc[dt] = mfma16(a, bv, cacc[dt]);
            }
        }
        __syncthreads();
    }

    // ---- epilogue: publish S, normalize p -> f32 attn in place
    if (lr == 0)
#pragma unroll
        for (int r = 0; r < 4; ++r) mh[w][lg * 4 + r][8] = s_run[r];

    float invS[4], mfin[4];
#pragma unroll
    for (int q = 0; q < 4; ++q) {
        const int r = q * 4 + (l >> 4);
        mfin[q] = mh[w][r][7];
        invS[q] = 1.0f / mh[w][r][8];
    }
    float* Af = A + ((size_t)bh * TT + i16c * 16) * TT;
#pragma unroll
    for (int t = 0; t < 8; ++t) {
        bf16x8 pv[4];
        float fac[4];
#pragma unroll
        for (int q = 0; q < 4; ++q) {
            const int r = q * 4 + (l >> 4), s = l & 15;
            pv[q] = *(const bf16x8*)(Aw + (size_t)r * 2048 + 1024 + t * 128 + s * 8);
            fac[q] = __expf(mh[w][r][t] - mfin[q]) * invS[q];
        }
        asm volatile("s_waitcnt vmcnt(0)" ::: "memory");
#pragma unroll
        for (int q = 0; q < 4; ++q) {
            const int r = q * 4 + (l >> 4), s = l & 15;
            f32x4 o0, o1;
#pragma unroll
            for (int ee = 0; ee < 4; ++ee) {
                o0[ee] = (float)pv[q][ee]     * fac[q];
                o1[ee] = (float)pv[q][4 + ee] * fac[q];
            }
            *(f32x4*)(Af + (size_t)r * TT + t * 128 + s * 8)     = o0;
            *(f32x4*)(Af + (size_t)r * TT + t * 128 + s * 8 + 4) = o1;
        }
    }

    // ---- ctx store
#pragma unroll
    for (int r = 0; r < 4; ++r) {
        const float is = 1.0f / s_run[r];
        const int row = iw + lg * 4 + r;
#pragma unroll
        for (int dt = 0; dt < 4; ++dt)
            ctx[((size_t)b * TT + row) * EE + hh * HDD + dt * 16 + lr] = (bf16)(cacc[dt][r] * is);
    }
}

// ---------------------------------------------------------------- k_out2
__global__ __launch_bounds__(256) void k_out2(
    const bf16* __restrict__ ctx, const bf16* __restrict__ woh,
    const float* __restrict__ bo, float* __restrict__ out)
{
    const int rb = blockIdx.x;
    const int cb = blockIdx.y;
    const int wid = threadIdx.x >> 6;
    const int l = threadIdx.x & 63;
    const int lg = l >> 4, lr = l & 15;
    const int row = rb * 64 + wid * 16 + lr;

    f32x4 acc[4];
#pragma unroll
    for (int c = 0; c < 4; ++c) acc[c] = f32x4{0.f,0.f,0.f,0.f};

    for (int ks = 0; ks < 16; ++ks) {
        const int e0 = ks * 32 + lg * 8;
        bf16x8 af = *(const bf16x8*)(ctx + (size_t)row * EE + e0);
#pragma unroll
        for (int c = 0; c < 4; ++c) {
            const int f = cb * 64 + c * 16 + lr;
            bf16x8 wf = *(const bf16x8*)(woh + (size_t)f * EE + e0);
            acc[c] = mfma16(af, wf, acc[c]);
        }
    }
#pragma unroll
    for (int c = 0; c < 4; ++c) {
        const int f = cb * 64 + c * 16 + lr;
        const float bov = bo[f];
#pragma unroll
        for (int r = 0; r < 4; ++r) {
            const int orow = rb * 64 + wid * 16 + lg * 4 + r;
            out[(size_t)orow * EE + f] = acc[c][r] + bov;
        }
    }
}

// ----------------------------------------------------------------
extern "C" void kernel_launch(void* const* d_in, const int* in_sizes, int n_in,
                              void* d_out, int out_size, void* d_ws, size_t ws_size,
                              hipStream_t stream)
{
    (void)in_sizes; (void)n_in; (void)out_size; (void)ws_size;
    const float* x  = (const float*)d_in[0];
    const float* u  = (const float*)d_in[1];
    const unsigned char* umask = (const unsigned char*)d_in[2];
    const float* wq = (const float*)d_in[3];
    const float* wk = (const float*)d_in[4];
    const float* wv = (const float*)d_in[5];
    const float* wo = (const float*)d_in[6];
    const float* bo = (const float*)d_in[7];
    const float* wu = (const float*)d_in[8];
    const float* bu = (const float*)d_in[9];

    float* out = (float*)d_out;
    float* A   = out + (size_t)BSZ * TT * EE;       // attn region of d_out

    const size_t qs  = (size_t)BSZ * HH * TT * HDD; // 4,194,304
    const size_t wsz = (size_t)EE * EE;             // 262,144
    bf16* Qh  = (bf16*)d_ws;
    bf16* Ql  = Qh + qs;
    bf16* Kh  = Ql + qs;
    bf16* Kl  = Kh + qs;
    bf16* Vt  = Kl + qs;
    bf16* ctx = Vt + qs;
    bf16* wqh = ctx + qs;
    bf16* wql = wqh + wsz;
    bf16* wkh = wql + wsz;
    bf16* wkl = wkh + wsz;
    bf16* wvh = wkl + wsz;
    bf16* woh = wvh + wsz;                          // ~53 MB total

    k_split_all<<<dim3(128, 4), 256, 0, stream>>>(wq, wk, wv, wo,
                                                  wqh, wql, wkh, wkl, wvh, woh);
    k_pre  <<<3072, 256, 0, stream>>>(u, umask, wu, bu, A,
                                      x, wqh, wql, wkh, wkl, wvh,
                                      Qh, Ql, Kh, Kl, Vt);
    kf10   <<<512, 512, 0, stream>>>(Qh, Ql, Kh, Kl, Vt, A, ctx);
    k_out2 <<<dim3(128, 8), 256, 0, stream>>>(ctx, woh, bo, out);
}

// Round 19
// 435.419 us; speedup vs baseline: 1.0818x; 1.0818x over previous
//
#include <hip/hip_runtime.h>
#include <cmath>

#define BSZ 8
#define TT  1024
#define EE  512
#define HH  8
#define CUc 6
#define HDD 64

typedef __bf16 bf16;
typedef __attribute__((ext_vector_type(4))) float f32x4;
typedef __attribute__((ext_vector_type(8))) float f32x8;
typedef __attribute__((ext_vector_type(4))) bf16  bf16x4;
typedef __attribute__((ext_vector_type(8))) bf16  bf16x8;

static __device__ __forceinline__ f32x4 mfma16(bf16x8 a, bf16x8 b, f32x4 c) {
    return __builtin_amdgcn_mfma_f32_16x16x32_bf16(a, b, c, 0, 0, 0);
}
static __device__ __forceinline__ void glds16(const bf16* g, bf16* l) {
    __builtin_amdgcn_global_load_lds((const __attribute__((address_space(1))) void*)g,
                                     (__attribute__((address_space(3))) void*)l, 16, 0, 0);
}

// ---------------------------------------------------------------- k_ubsp: ubias (z<8) + weight-split (z==8)
// ubias role identical to R17 k_ubias2; split role = R17 k_split_all folded in (2 chunks per block).
__global__ __launch_bounds__(256) void k_ubsp(
    const float* __restrict__ u, const unsigned char* __restrict__ umask,
    const float* __restrict__ wu, const float* __restrict__ bu,
    float* __restrict__ A,
    const float* __restrict__ wq, const float* __restrict__ wk,
    const float* __restrict__ wv, const float* __restrict__ wo,
    bf16* __restrict__ wqh, bf16* __restrict__ wql,
    bf16* __restrict__ wkh, bf16* __restrict__ wkl,
    bf16* __restrict__ wvh, bf16* __restrict__ woh)
{
    if (blockIdx.z == 8) {
        // ---------------- split role: 256 blocks x 2 chunks ----------------
        const int zi = blockIdx.y * 16 + blockIdx.x;      // 0..255
#pragma unroll
        for (int it = 0; it < 2; ++it) {
            const int gid = zi * 2 + it;                  // 0..511
            const int mat = gid >> 7;                     // 0..3
            const int blk = gid & 127;
            const float* src; bf16* hi; bf16* lo;
            switch (mat) {
                case 0: src = wq; hi = wqh; lo = wql;     break;
                case 1: src = wk; hi = wkh; lo = wkl;     break;
                case 2: src = wv; hi = wvh; lo = nullptr; break;
                default: src = wo; hi = woh; lo = nullptr; break;
            }
            const int i = (blk * 256 + threadIdx.x) * 8;  // < 262144*8? 128*256*8 = 262144 elems ✓
            f32x8 v = *(const f32x8*)(src + i);
            bf16x8 h8, l8;
#pragma unroll
            for (int k = 0; k < 8; ++k) {
                bf16 h = (bf16)v[k];
                h8[k] = h;
                l8[k] = (bf16)(v[k] - (float)h);
            }
            *(bf16x8*)(hi + i) = h8;
            if (lo) *(bf16x8*)(lo + i) = l8;
        }
        return;
    }

    // ---------------- ubias role (identical to R17) ----------------
    __shared__ __align__(16) unsigned char msk[64][64];   // [j-rel][i-rel]
    const int b  = blockIdx.z;
    const int i0 = blockIdx.y * 64;
    const int j0 = blockIdx.x * 64;
    const int t  = threadIdx.x;

    {
        const int jj  = t >> 2;
        const int seg = (t & 3) * 16;
        *(uint4*)(&msk[jj][seg]) =
            *(const uint4*)(umask + ((size_t)b * TT + (j0 + jj)) * TT + i0 + seg);
    }
    float wuv[HH][CUc], buv[HH];
#pragma unroll
    for (int h = 0; h < HH; ++h) {
        buv[h] = bu[h];
#pragma unroll
        for (int c = 0; c < CUc; ++c) wuv[h][c] = wu[h * CUc + c];
    }
    __syncthreads();

    const int j = j0 + (t & 63);
    for (int ii = (t >> 6); ii < 64; ii += 4) {
        const int i = i0 + ii;
        float uv[CUc];
#pragma unroll
        for (int c = 0; c < CUc; ++c)
            uv[c] = u[(((size_t)b * CUc + c) * TT + i) * TT + j];
        const bool mk = msk[t & 63][ii] != 0;
#pragma unroll
        for (int h = 0; h < HH; ++h) {
            float v = buv[h];
#pragma unroll
            for (int c = 0; c < CUc; ++c) v += uv[c] * wuv[h][c];
            if (mk) v = -INFINITY;
            bf16* ub = (bf16*)(A + ((size_t)(b * HH + h) * TT + (i & ~15)) * TT);
            ub[(i & 15) * TT + j] = (bf16)v;
        }
    }
}

// ---------------------------------------------------------------- k_proj2 (f32 x, in-reg split)
__global__ __launch_bounds__(256) void k_proj2(
    const float* __restrict__ x,
    const bf16* __restrict__ wqh, const bf16* __restrict__ wql,
    const bf16* __restrict__ wkh, const bf16* __restrict__ wkl,
    const bf16* __restrict__ wvh,
    bf16* __restrict__ Qh, bf16* __restrict__ Ql,
    bf16* __restrict__ Kh, bf16* __restrict__ Kl,
    bf16* __restrict__ Vt)
{
    const int rb = blockIdx.x;
    const int cb = blockIdx.y;
    const int wid = threadIdx.x >> 6;
    const int l   = threadIdx.x & 63;
    const int lg = l >> 4, lr = l & 15;
    const int row = rb * 64 + wid * 16 + lr;

    f32x4 aq[4], ak[4], av[4];
#pragma unroll
    for (int c = 0; c < 4; ++c) {
        aq[c] = f32x4{0.f,0.f,0.f,0.f}; ak[c] = f32x4{0.f,0.f,0.f,0.f}; av[c] = f32x4{0.f,0.f,0.f,0.f};
    }

    for (int ks = 0; ks < 16; ++ks) {
        const int e0 = ks * 32 + lg * 8;
        f32x8 xv = *(const f32x8*)(x + (size_t)row * EE + e0);
        bf16x8 xh, xl;
#pragma unroll
        for (int i = 0; i < 8; ++i) {
            bf16 h = (bf16)xv[i];
            xh[i] = h;
            xl[i] = (bf16)(xv[i] - (float)h);
        }
#pragma unroll
        for (int c = 0; c < 4; ++c) {
            const int f = cb * 64 + c * 16 + lr;
            const size_t wo = (size_t)f * EE + e0;
            bf16x8 qh = *(const bf16x8*)(wqh + wo);
            bf16x8 ql = *(const bf16x8*)(wql + wo);
            bf16x8 kh = *(const bf16x8*)(wkh + wo);
            bf16x8 kl = *(const bf16x8*)(wkl + wo);
            bf16x8 vh = *(const bf16x8*)(wvh + wo);
            aq[c] = mfma16(xh, qh, aq[c]); aq[c] = mfma16(xh, ql, aq[c]); aq[c] = mfma16(xl, qh, aq[c]);
            ak[c] = mfma16(xh, kh, ak[c]); ak[c] = mfma16(xh, kl, ak[c]); ak[c] = mfma16(xl, kh, ak[c]);
            av[c] = mfma16(xh, vh, av[c]);
        }
    }

#pragma unroll
    for (int c = 0; c < 4; ++c)
#pragma unroll
        for (int r = 0; r < 4; ++r) {
            const int orow = rb * 64 + wid * 16 + lg * 4 + r;
            const int b = orow >> 10, t = orow & 1023;
            const int f = cb * 64 + c * 16 + lr;
            const int h = f >> 6, d = f & 63;
            const size_t idx = ((size_t)(b * HH + h) * TT + t) * HDD + d;
            float vq = aq[c][r];
            bf16 qhi = (bf16)vq; Qh[idx] = qhi; Ql[idx] = (bf16)(vq - (float)qhi);
            float vk = ak[c][r];
            bf16 khi = (bf16)vk; Kh[idx] = khi; Kl[idx] = (bf16)(vk - (float)khi);
            Vt[(((size_t)(b * HH + h) * HDD + d) * TT) + t] = (bf16)av[c][r];
        }
}

// ---------------------------------------------------------------- kf10: LDS-tiled flash attention (frozen)
__global__ __launch_bounds__(512, 1) void kf10(
    const bf16* __restrict__ Qh, const bf16* __restrict__ Ql,
    const bf16* __restrict__ Kh, const bf16* __restrict__ Kl,
    const bf16* __restrict__ Vt,
    float* __restrict__ A, bf16* __restrict__ ctx)
{
    const int g  = blockIdx.x;
    const int b  = g & 7;                 // XCD g%8 -> batch b (K/V/Q L2-local)
    const int hh = g >> 6;                // head, changes slowest
    const int ib = (g >> 3) & 7;
    const int bh = b * HH + hh;
    const int i0 = ib * 128;
    const int w  = threadIdx.x >> 6;
    const int l  = threadIdx.x & 63;
    const int lg = l >> 4, lr = l & 15;
    const int i16c = ib * 8 + w;          // wave's 16-row chunk id
    const int iw   = i0 + w * 16;

    __shared__ __align__(16) bf16 KHL[2][8192];   // [buf][row*64 + slot*8], slot = seg^(row&7)
    __shared__ __align__(16) bf16 KLL[2][8192];
    __shared__ __align__(16) bf16 VL [2][8192];   // [buf][d*128 + slot*8], slot=(s&8)|((s^(d&7))&7)
    __shared__ __align__(16) bf16 P  [8][2048];   // per-wave 16x128, same XOR scheme
    __shared__ float mh[8][16][12];               // [w][row][tile0..7, 8=S]

    const bf16* KhG = Kh + (size_t)bh * TT * HDD;
    const bf16* KlG = Kl + (size_t)bh * TT * HDD;
    const bf16* VtG = Vt + (size_t)bh * HDD * TT;
    bf16* Aw = (bf16*)(A + ((size_t)bh * TT + i16c * 16) * TT);  // wave's 16-row span (64KB)

    // ---- Q fragments (once)
    const bf16* qph = Qh + ((size_t)bh * TT + iw) * HDD;
    const bf16* qpl = Ql + ((size_t)bh * TT + iw) * HDD;
    bf16x8 qh0 = *(const bf16x8*)(qph + lr * HDD + lg * 8);
    bf16x8 qh1 = *(const bf16x8*)(qph + lr * HDD + 32 + lg * 8);
    bf16x8 ql0 = *(const bf16x8*)(qpl + lr * HDD + lg * 8);
    bf16x8 ql1 = *(const bf16x8*)(qpl + lr * HDD + 32 + lg * 8);

    // ---- staging: wave handles units w*6 .. w*6+5 (48 x 1KB per tile)
    auto stage = [&](int buf, int t) {
        const int j0 = t * 128;
#pragma unroll
        for (int k = 0; k < 6; ++k) {
            const int gu = w * 6 + k;
            if (gu < 16) {                     // Kh: unit u = 8 rows of 128B
                const int u = gu;
                const int jr = u * 8 + (l >> 3), s = l & 7;
                glds16(KhG + (size_t)(j0 + jr) * HDD + ((s ^ (jr & 7)) * 8),
                       &KHL[buf][u * 512]);
            } else if (gu < 32) {
                const int u = gu - 16;
                const int jr = u * 8 + (l >> 3), s = l & 7;
                glds16(KlG + (size_t)(j0 + jr) * HDD + ((s ^ (jr & 7)) * 8),
                       &KLL[buf][u * 512]);
            } else {                           // V: unit u = 4 rows of 256B
                const int u = gu - 32;
                const int d = u * 4 + (l >> 4), s = l & 15;
                const int q = (s & 8) | ((s ^ (d & 7)) & 7);
                glds16(VtG + (size_t)d * TT + j0 + q * 8,
                       &VL[buf][u * 512]);
            }
        }
    };

    float m_run[4], s_run[4];
    f32x4 cacc[4];
#pragma unroll
    for (int r = 0; r < 4; ++r) { m_run[r] = -INFINITY; s_run[r] = 0.f; }
#pragma unroll
    for (int dt = 0; dt < 4; ++dt) cacc[dt] = f32x4{0.f,0.f,0.f,0.f};

    stage(0, 0);
    __syncthreads();

    for (int t = 0; t < 8; ++t) {
        const int buf = t & 1;

        // UB tile loads (global, consumed after QK^T)
        bf16x8 ubr[4];
#pragma unroll
        for (int q = 0; q < 4; ++q) {
            const int r = q * 4 + (l >> 4), s = l & 15;
            ubr[q] = *(const bf16x8*)(Aw + (size_t)r * TT + t * 128 + s * 8);
        }
        if (t < 7) stage(buf ^ 1, t + 1);

        // ---- QK^T from swizzled LDS
        f32x4 s8[8];
#pragma unroll
        for (int jt2 = 0; jt2 < 8; ++jt2) {
            const int jr = jt2 * 16 + lr;
            const int x7 = jr & 7;
            bf16x8 kh0 = *(const bf16x8*)&KHL[buf][jr * 64 + ((lg       ^ x7) * 8)];
            bf16x8 kh1 = *(const bf16x8*)&KHL[buf][jr * 64 + (((lg + 4) ^ x7) * 8)];
            bf16x8 kl0 = *(const bf16x8*)&KLL[buf][jr * 64 + ((lg       ^ x7) * 8)];
            bf16x8 kl1 = *(const bf16x8*)&KLL[buf][jr * 64 + (((lg + 4) ^ x7) * 8)];
            f32x4 acc = f32x4{0.f,0.f,0.f,0.f};
            acc = mfma16(qh0, kh0, acc); acc = mfma16(qh1, kh1, acc);
            acc = mfma16(qh0, kl0, acc); acc = mfma16(qh1, kl1, acc);
            acc = mfma16(ql0, kh0, acc); acc = mfma16(ql1, kh1, acc);
            s8[jt2] = acc;
        }

        // ---- ub add: bounce ubr through P[w] (transposed, XOR layout)
#pragma unroll
        for (int q = 0; q < 4; ++q) {
            const int r = q * 4 + (l >> 4), s = l & 15;
            const int slot = (s & 8) | ((s ^ (r & 7)) & 7);
            *(bf16x8*)&P[w][r * 128 + slot * 8] = ubr[q];
        }
#pragma unroll
        for (int jt2 = 0; jt2 < 8; ++jt2)
#pragma unroll
            for (int r = 0; r < 4; ++r) {
                const int row = lg * 4 + r, col = jt2 * 16 + lr;
                const int sg = col >> 3;
                const int slot = (sg & 8) | ((sg ^ (row & 7)) & 7);
                s8[jt2][r] = s8[jt2][r] * 8.0f + (float)P[w][row * 128 + slot * 8 + (col & 7)];
            }

        // ---- online softmax
        float tm[4];
#pragma unroll
        for (int r = 0; r < 4; ++r) {
            float mm = s8[0][r];
#pragma unroll
            for (int jt2 = 1; jt2 < 8; ++jt2) mm = fmaxf(mm, s8[jt2][r]);
            tm[r] = mm;
        }
#pragma unroll
        for (int off = 1; off < 16; off <<= 1)
#pragma unroll
            for (int r = 0; r < 4; ++r) tm[r] = fmaxf(tm[r], __shfl_xor(tm[r], off));
        float mnew[4], mexp[4], e[4];
#pragma unroll
        for (int r = 0; r < 4; ++r) {
            mnew[r] = fmaxf(m_run[r], tm[r]);
            mexp[r] = (mnew[r] == -INFINITY) ? 0.f : mnew[r];
            e[r]    = (m_run[r] == -INFINITY) ? 0.f : __expf(m_run[r] - mexp[r]);
            m_run[r] = mnew[r];
        }
#pragma unroll
        for (int dt = 0; dt < 4; ++dt)
#pragma unroll
            for (int r = 0; r < 4; ++r) cacc[dt][r] *= e[r];

        float psum[4] = {0.f, 0.f, 0.f, 0.f};
#pragma unroll
        for (int jt2 = 0; jt2 < 8; ++jt2)
#pragma unroll
            for (int r = 0; r < 4; ++r) {
                const float p = __expf(s8[jt2][r] - mexp[r]);
                psum[r] += p;
                const int row = lg * 4 + r, col = jt2 * 16 + lr;
                const int sg = col >> 3;
                const int slot = (sg & 8) | ((sg ^ (row & 7)) & 7);
                P[w][row * 128 + slot * 8 + (col & 7)] = (bf16)p;
            }
#pragma unroll
        for (int off = 1; off < 16; off <<= 1)
#pragma unroll
            for (int r = 0; r < 4; ++r) psum[r] += __shfl_xor(psum[r], off);
#pragma unroll
        for (int r = 0; r < 4; ++r) s_run[r] = s_run[r] * e[r] + psum[r];
        if (lr == 0)
#pragma unroll
            for (int r = 0; r < 4; ++r) mh[w][lg * 4 + r][t] = mnew[r];

        // ---- park p (bf16) in the spare half of the f32 row-span
#pragma unroll
        for (int q = 0; q < 4; ++q) {
            const int r = q * 4 + (l >> 4), s = l & 15;
            const int slot = (s & 8) | ((s ^ (r & 7)) & 7);
            bf16x8 pv = *(const bf16x8*)&P[w][r * 128 + slot * 8];
            *(bf16x8*)(Aw + (size_t)r * 2048 + 1024 + t * 128 + s * 8) = pv;
        }

        // ---- PV from swizzled P and V
#pragma unroll
        for (int ks = 0; ks < 4; ++ks) {
            const int sg = ks * 4 + lg;
            const int ps = (sg & 8) | ((sg ^ (lr & 7)) & 7);
            bf16x8 a = *(const bf16x8*)&P[w][lr * 128 + ps * 8];
#pragma unroll
            for (int dt = 0; dt < 4; ++dt) {
                const int d = dt * 16 + lr;
                const int vs = (sg & 8) | ((sg ^ (d & 7)) & 7);
                bf16x8 bv = *(const bf16x8*)&VL[buf][d * 128 + vs * 8];
                cacc[dt] = mfma16(a, bv, cacc[dt]);
            }
        }
        __syncthreads();
    }

    // ---- epilogue: publish S, normalize p -> f32 attn in place
    if (lr == 0)
#pragma unroll
        for (int r = 0; r < 4; ++r) mh[w][lg * 4 + r][8] = s_run[r];

    float invS[4], mfin[4];
#pragma unroll
    for (int q = 0; q < 4; ++q) {
        const int r = q * 4 + (l >> 4);
        mfin[q] = mh[w][r][7];
        invS[q] = 1.0f / mh[w][r][8];
    }
    float* Af = A + ((size_t)bh * TT + i16c * 16) * TT;
#pragma unroll
    for (int t = 0; t < 8; ++t) {
        bf16x8 pv[4];
        float fac[4];
#pragma unroll
        for (int q = 0; q < 4; ++q) {
            const int r = q * 4 + (l >> 4), s = l & 15;
            pv[q] = *(const bf16x8*)(Aw + (size_t)r * 2048 + 1024 + t * 128 + s * 8);
            fac[q] = __expf(mh[w][r][t] - mfin[q]) * invS[q];
        }
        asm volatile("s_waitcnt vmcnt(0)" ::: "memory");
#pragma unroll
        for (int q = 0; q < 4; ++q) {
            const int r = q * 4 + (l >> 4), s = l & 15;
            f32x4 o0, o1;
#pragma unroll
            for (int ee = 0; ee < 4; ++ee) {
                o0[ee] = (float)pv[q][ee]     * fac[q];
                o1[ee] = (float)pv[q][4 + ee] * fac[q];
            }
            *(f32x4*)(Af + (size_t)r * TT + t * 128 + s * 8)     = o0;
            *(f32x4*)(Af + (size_t)r * TT + t * 128 + s * 8 + 4) = o1;
        }
    }

    // ---- ctx store
#pragma unroll
    for (int r = 0; r < 4; ++r) {
        const float is = 1.0f / s_run[r];
        const int row = iw + lg * 4 + r;
#pragma unroll
        for (int dt = 0; dt < 4; ++dt)
            ctx[((size_t)b * TT + row) * EE + hh * HDD + dt * 16 + lr] = (bf16)(cacc[dt][r] * is);
    }
}

// ---------------------------------------------------------------- k_out2
__global__ __launch_bounds__(256) void k_out2(
    const bf16* __restrict__ ctx, const bf16* __restrict__ woh,
    const float* __restrict__ bo, float* __restrict__ out)
{
    const int rb = blockIdx.x;
    const int cb = blockIdx.y;
    const int wid = threadIdx.x >> 6;
    const int l = threadIdx.x & 63;
    const int lg = l >> 4, lr = l & 15;
    const int row = rb * 64 + wid * 16 + lr;

    f32x4 acc[4];
#pragma unroll
    for (int c = 0; c < 4; ++c) acc[c] = f32x4{0.f,0.f,0.f,0.f};

    for (int ks = 0; ks < 16; ++ks) {
        const int e0 = ks * 32 + lg * 8;
        bf16x8 af = *(const bf16x8*)(ctx + (size_t)row * EE + e0);
#pragma unroll
        for (int c = 0; c < 4; ++c) {
            const int f = cb * 64 + c * 16 + lr;
            bf16x8 wf = *(const bf16x8*)(woh + (size_t)f * EE + e0);
            acc[c] = mfma16(af, wf, acc[c]);
        }
    }
#pragma unroll
    for (int c = 0; c < 4; ++c) {
        const int f = cb * 64 + c * 16 + lr;
        const float bov = bo[f];
#pragma unroll
        for (int r = 0; r < 4; ++r) {
            const int orow = rb * 64 + wid * 16 + lg * 4 + r;
            out[(size_t)orow * EE + f] = acc[c][r] + bov;
        }
    }
}

// ----------------------------------------------------------------
extern "C" void kernel_launch(void* const* d_in, const int* in_sizes, int n_in,
                              void* d_out, int out_size, void* d_ws, size_t ws_size,
                              hipStream_t stream)
{
    (void)in_sizes; (void)n_in; (void)out_size; (void)ws_size;
    const float* x  = (const float*)d_in[0];
    const float* u  = (const float*)d_in[1];
    const unsigned char* umask = (const unsigned char*)d_in[2];
    const float* wq = (const float*)d_in[3];
    const float* wk = (const float*)d_in[4];
    const float* wv = (const float*)d_in[5];
    const float* wo = (const float*)d_in[6];
    const float* bo = (const float*)d_in[7];
    const float* wu = (const float*)d_in[8];
    const float* bu = (const float*)d_in[9];

    float* out = (float*)d_out;
    float* A   = out + (size_t)BSZ * TT * EE;       // attn region of d_out

    const size_t qs  = (size_t)BSZ * HH * TT * HDD; // 4,194,304
    const size_t wsz = (size_t)EE * EE;             // 262,144
    bf16* Qh  = (bf16*)d_ws;
    bf16* Ql  = Qh + qs;
    bf16* Kh  = Ql + qs;
    bf16* Kl  = Kh + qs;
    bf16* Vt  = Kl + qs;
    bf16* ctx = Vt + qs;
    bf16* wqh = ctx + qs;
    bf16* wql = wqh + wsz;
    bf16* wkh = wql + wsz;
    bf16* wkl = wkh + wsz;
    bf16* wvh = wkl + wsz;
    bf16* woh = wvh + wsz;                          // ~53 MB total

    k_ubsp <<<dim3(16, 16, 9), 256, 0, stream>>>(u, umask, wu, bu, A,
                                                 wq, wk, wv, wo,
                                                 wqh, wql, wkh, wkl, wvh, woh);
    k_proj2<<<dim3(128, 8), 256, 0, stream>>>(x, wqh, wql, wkh, wkl, wvh, Qh, Ql, Kh, Kl, Vt);
    kf10   <<<512, 512, 0, stream>>>(Qh, Ql, Kh, Kl, Vt, A, ctx);
    k_out2 <<<dim3(128, 8), 256, 0, stream>>>(ctx, woh, bo, out);
}